// Round 3
// baseline (293.693 us; speedup 1.0000x reference)
//
#include <hip/hip_runtime.h>

typedef unsigned short u16;
typedef unsigned int u32;

typedef __bf16 bf16x8 __attribute__((ext_vector_type(8)));
typedef float f32x16 __attribute__((ext_vector_type(16)));

#define OUT_F 4096
#define IN_F 4096
#define M_ROWS 4096              // 2 * 2048
#define NUM_GROUPS ((OUT_F * IN_F) / 32)   // 524288
#define NUM_TRIPLETS (NUM_GROUPS * 4)      // 2097152, one per 8 weights

// ---------- helpers ----------

__device__ __forceinline__ u16 f2bf(float f) {
    union { float f; u32 u; } c; c.f = f;
    u32 u = c.u;
    u += 0x7fffu + ((u >> 16) & 1u);   // round-to-nearest-even (finite inputs)
    return (u16)(u >> 16);
}

__device__ __forceinline__ u32 pk2(float a, float b) {
    return (u32)f2bf(a) | ((u32)f2bf(b) << 16);
}

// async global -> LDS, 16 bytes per lane (global_load_lds_dwordx4)
__device__ __forceinline__ void async_copy16(const u16* g, u16* l) {
    __builtin_amdgcn_global_load_lds(
        (const __attribute__((address_space(1))) u32*)g,
        (__attribute__((address_space(3))) u32*)l,
        16, 0, 0);
}

// ---------- fused prep ----------
// blocks [0, 8192): dequant — one thread per byte-triplet (8 weights),
//   each thread writes ONE contiguous 16B uint4 (perfect store coalescing).
// blocks [8192, 16384): x fp32 -> bf16, one thread per 8 elements.
__global__ __launch_bounds__(256) void prep_kernel(
        const float* __restrict__ x, const int* __restrict__ q,
        const float* __restrict__ scales,
        u16* __restrict__ W, u16* __restrict__ Xb) {
    int bid = blockIdx.x;
    int tid = threadIdx.x;
    if (bid < 8192) {
        // ---- dequant: triplet t -> weights [t*8, t*8+8) ----
        int t = bid * 256 + tid;                 // [0, NUM_TRIPLETS)
        int b0 = q[3 * t];
        int b1 = q[3 * t + 1];
        int b2 = q[3 * t + 2];
        float mv = scales[t >> 2];
        float s = mv * (2.0f / 7.0f);            // w = v*s - mv
        float o = -mv;

        int v0 = b0 & 7;
        int v1 = (b0 >> 3) & 7;
        int v2 = ((b0 >> 6) & 3) | ((b1 & 1) << 2);
        int v3 = (b1 >> 1) & 7;
        int v4 = (b1 >> 4) & 7;
        int v5 = ((b1 >> 7) & 1) | ((b2 & 3) << 1);
        int v6 = (b2 >> 2) & 7;
        int v7 = (b2 >> 5) & 7;
        uint4 w;
        w.x = pk2(fmaf((float)v0, s, o), fmaf((float)v1, s, o));
        w.y = pk2(fmaf((float)v2, s, o), fmaf((float)v3, s, o));
        w.z = pk2(fmaf((float)v4, s, o), fmaf((float)v5, s, o));
        w.w = pk2(fmaf((float)v6, s, o), fmaf((float)v7, s, o));
        ((uint4*)W)[t] = w;
    } else {
        // ---- x fp32 -> bf16, 8 elements/thread ----
        int i = (bid - 8192) * 256 + tid;
        const float4* p = (const float4*)x + (size_t)i * 2;
        float4 u = p[0], v = p[1];
        uint4 w;
        w.x = pk2(u.x, u.y);
        w.y = pk2(u.z, u.w);
        w.z = pk2(v.x, v.y);
        w.w = pk2(v.z, v.w);
        ((uint4*)Xb)[i] = w;
    }
}

// ---------- bf16 GEMM: C[m][n] = sum_k A[m][k]*B[n][k] + bias[n] ----------
// A: [M_ROWS][IN_F] bf16 row-major (x), B: [OUT_F][IN_F] bf16 row-major (W)
// block = 256 threads (4 waves), tile 128x128, BK=64, MFMA 32x32x16.
// Each wave computes a 64x64 subtile as 2x2 MFMA tiles of 32x32 (f32x16 acc).
// LDS tiles stored as 16B "chunks": slot s = row*8 + pc, content of physical
// chunk pc is logical k-chunk lc = pc ^ (row & 7) (XOR swizzle applied on the
// global source address; global_load_lds forces lane-contiguous LDS dest).
// Measured (R1/R2): 0 bank conflicts with this pattern.
__global__ __launch_bounds__(256) void gemm_bt_kernel(
        const u16* __restrict__ A, const u16* __restrict__ B,
        const float* __restrict__ bias, float* __restrict__ C) {
    __shared__ u16 sA[128 * 64];
    __shared__ u16 sB[128 * 64];

    const int tid = threadIdx.x;
    const int lane = tid & 63;
    const int w = tid >> 6;          // wave 0..3
    const int wr = w >> 1;           // wave row 0..1
    const int wc = w & 1;            // wave col 0..1
    const int l31 = lane & 31;
    const int hi = lane >> 5;
    const int lnx = lane & 7;

    const int mb = blockIdx.y * 128;
    const int nb = blockIdx.x * 128;

    // staging geometry: 4 passes x 256 threads x 16B = 16KB = 128 rows x 64 bf16
    int offg[4];   // element offset within matrix block (add ko each iter)
    int offl[4];   // ushort offset within LDS tile
#pragma unroll
    for (int p = 0; p < 4; ++p) {
        int slot = p * 256 + tid;        // [0,1024)
        int row = slot >> 3;             // [0,128)
        int pc = slot & 7;               // physical 16B chunk in row
        int lc = pc ^ (row & 7);         // logical k-chunk (XOR swizzle)
        offg[p] = row * IN_F + lc * 8;
        offl[p] = slot * 8;              // = row*64 + pc*8
    }
    const u16* baseA = A + (size_t)mb * IN_F;
    const u16* baseB = B + (size_t)nb * IN_F;

    // bias for this thread's 2 output column groups
    float bj[2];
#pragma unroll
    for (int j = 0; j < 2; ++j)
        bj[j] = bias[nb + wc * 64 + j * 32 + l31];

    // fragment read row bases (ushort offsets; row stride = 64 ushorts)
    // A-operand mapping for 32x32x16: m = lane&31, k = (lane>>5)*8 + j
    int arow[2], brow[2];
#pragma unroll
    for (int i = 0; i < 2; ++i) {
        arow[i] = (wr * 64 + i * 32 + l31) * 64;
        brow[i] = (wc * 64 + i * 32 + l31) * 64;
    }

    f32x16 acc[2][2];
#pragma unroll
    for (int i = 0; i < 2; ++i)
#pragma unroll
        for (int j = 0; j < 2; ++j) acc[i][j] = (f32x16)0.0f;

    for (int ko = 0; ko < IN_F; ko += 64) {
#pragma unroll
        for (int p = 0; p < 4; ++p)
            async_copy16(baseA + offg[p] + ko, &sA[offl[p]]);
#pragma unroll
        for (int p = 0; p < 4; ++p)
            async_copy16(baseB + offg[p] + ko, &sB[offl[p]]);
        __syncthreads();

#pragma unroll
        for (int s = 0; s < 4; ++s) {
            // lane supplies k = s*16 + hi*8 + j  ->  logical chunk s*2 + hi
            const int pc8 = ((s * 2 + hi) ^ lnx) * 8;
            bf16x8 av[2], bv[2];
#pragma unroll
            for (int i = 0; i < 2; ++i)
                av[i] = *(const bf16x8*)&sA[arow[i] + pc8];
#pragma unroll
            for (int j = 0; j < 2; ++j)
                bv[j] = *(const bf16x8*)&sB[brow[j] + pc8];
#pragma unroll
            for (int i = 0; i < 2; ++i)
#pragma unroll
                for (int j = 0; j < 2; ++j)
                    acc[i][j] = __builtin_amdgcn_mfma_f32_32x32x16_bf16(
                        av[i], bv[j], acc[i][j], 0, 0, 0);
        }
        __syncthreads();
    }

    // epilogue: C/D layout col = lane&31, row = (reg&3) + 8*(reg>>2) + 4*hi
#pragma unroll
    for (int i = 0; i < 2; ++i) {
#pragma unroll
        for (int j = 0; j < 2; ++j) {
            int col = nb + wc * 64 + j * 32 + l31;
#pragma unroll
            for (int qd = 0; qd < 4; ++qd) {
                int rowb = mb + wr * 64 + i * 32 + 8 * qd + 4 * hi;
                float* cp = C + (size_t)rowb * OUT_F + col;
#pragma unroll
                for (int r = 0; r < 4; ++r)
                    cp[(size_t)r * OUT_F] = acc[i][j][4 * qd + r] + bj[j];
            }
        }
    }
}

extern "C" void kernel_launch(void* const* d_in, const int* in_sizes, int n_in,
                              void* d_out, int out_size, void* d_ws, size_t ws_size,
                              hipStream_t stream) {
    const float* x = (const float*)d_in[0];       // [2,2048,4096] fp32
    const int* wq = (const int*)d_in[1];          // [NUM_GROUPS*12]
    const float* wn = (const float*)d_in[2];      // [NUM_GROUPS]
    const float* bias = (const float*)d_in[3];    // [4096]
    float* out = (float*)d_out;                   // [2,2048,4096] fp32

    u16* Wb = (u16*)d_ws;                         // 32 MB
    u16* Xb = Wb + (size_t)OUT_F * IN_F;          // 32 MB

    // 8192 dequant blocks + 8192 cvt blocks in one launch
    prep_kernel<<<16384, 256, 0, stream>>>(x, wq, wn, Wb, Xb);
    gemm_bt_kernel<<<dim3(OUT_F / 128, M_ROWS / 128), 256, 0, stream>>>(
        Xb, Wb, bias, out);
}

// Round 4
// 282.757 us; speedup vs baseline: 1.0387x; 1.0387x over previous
//
#include <hip/hip_runtime.h>

typedef unsigned short u16;
typedef unsigned int u32;

typedef __bf16 bf16x8 __attribute__((ext_vector_type(8)));
typedef float f32x4 __attribute__((ext_vector_type(4)));

#define OUT_F 4096
#define IN_F 4096
#define M_ROWS 4096              // 2 * 2048
#define NUM_GROUPS ((OUT_F * IN_F) / 32)   // 524288

// ---------- helpers ----------

__device__ __forceinline__ u16 f2bf(float f) {
    union { float f; u32 u; } c; c.f = f;
    u32 u = c.u;
    u += 0x7fffu + ((u >> 16) & 1u);   // round-to-nearest-even (finite inputs)
    return (u16)(u >> 16);
}

__device__ __forceinline__ u32 pk2(float a, float b) {
    return (u32)f2bf(a) | ((u32)f2bf(b) << 16);
}

// async global -> LDS, 16 bytes per lane (global_load_lds_dwordx4)
__device__ __forceinline__ void async_copy16(const u16* g, u16* l) {
    __builtin_amdgcn_global_load_lds(
        (const __attribute__((address_space(1))) u32*)g,
        (__attribute__((address_space(3))) u32*)l,
        16, 0, 0);
}

// ---------- fused prep ----------
// blocks [0, 8192): dequant — one thread per byte-triplet (8 weights),
//   each thread writes ONE contiguous 16B uint4 (perfect store coalescing).
// blocks [8192, 16384): x fp32 -> bf16, one thread per 8 elements.
__global__ __launch_bounds__(256) void prep_kernel(
        const float* __restrict__ x, const int* __restrict__ q,
        const float* __restrict__ scales,
        u16* __restrict__ W, u16* __restrict__ Xb) {
    int bid = blockIdx.x;
    int tid = threadIdx.x;
    if (bid < 8192) {
        // ---- dequant: triplet t -> weights [t*8, t*8+8) ----
        int t = bid * 256 + tid;                 // [0, NUM_TRIPLETS)
        int b0 = q[3 * t];
        int b1 = q[3 * t + 1];
        int b2 = q[3 * t + 2];
        float mv = scales[t >> 2];
        float s = mv * (2.0f / 7.0f);            // w = v*s - mv
        float o = -mv;

        int v0 = b0 & 7;
        int v1 = (b0 >> 3) & 7;
        int v2 = ((b0 >> 6) & 3) | ((b1 & 1) << 2);
        int v3 = (b1 >> 1) & 7;
        int v4 = (b1 >> 4) & 7;
        int v5 = ((b1 >> 7) & 1) | ((b2 & 3) << 1);
        int v6 = (b2 >> 2) & 7;
        int v7 = (b2 >> 5) & 7;
        uint4 w;
        w.x = pk2(fmaf((float)v0, s, o), fmaf((float)v1, s, o));
        w.y = pk2(fmaf((float)v2, s, o), fmaf((float)v3, s, o));
        w.z = pk2(fmaf((float)v4, s, o), fmaf((float)v5, s, o));
        w.w = pk2(fmaf((float)v6, s, o), fmaf((float)v7, s, o));
        ((uint4*)W)[t] = w;
    } else {
        // ---- x fp32 -> bf16, 8 elements/thread ----
        int i = (bid - 8192) * 256 + tid;
        const float4* p = (const float4*)x + (size_t)i * 2;
        float4 u = p[0], v = p[1];
        uint4 w;
        w.x = pk2(u.x, u.y);
        w.y = pk2(u.z, u.w);
        w.z = pk2(v.x, v.y);
        w.w = pk2(v.z, v.w);
        ((uint4*)Xb)[i] = w;
    }
}

// ---------- bf16 GEMM: C[m][n] = sum_k A[m][k]*B[n][k] + bias[n] ----------
// A: [M_ROWS][IN_F] bf16 row-major (x), B: [OUT_F][IN_F] bf16 row-major (W)
// block = 256 threads (4 waves), tile 128x128, BK=64, MFMA 16x16x32.
// R3 post-mortem: 32x32x16 MFMA gave identical time + 1.7e7 bank conflicts;
// binding resource is LDS port traffic (12.9 GB total) + barrier drain, not
// MFMA issue count. This 16x16 variant measured ZERO conflicts (R1/R2).
// LDS tiles stored as 16B "chunks": slot s = row*8 + pc, content of physical
// chunk pc is logical k-chunk lc = pc ^ (row & 7) (XOR swizzle applied on the
// global source address; global_load_lds forces lane-contiguous LDS dest).
__global__ __launch_bounds__(256) void gemm_bt_kernel(
        const u16* __restrict__ A, const u16* __restrict__ B,
        const float* __restrict__ bias, float* __restrict__ C) {
    __shared__ u16 sA[128 * 64];
    __shared__ u16 sB[128 * 64];

    const int tid = threadIdx.x;
    const int lane = tid & 63;
    const int w = tid >> 6;          // wave 0..3
    const int wr = w >> 1;           // wave row 0..1
    const int wc = w & 1;            // wave col 0..1
    const int ln = lane & 15;
    const int quad = lane >> 4;

    const int mb = blockIdx.y * 128;
    const int nb = blockIdx.x * 128;

    // staging geometry: 4 passes x 256 threads x 16B = 16KB = 128 rows x 64 bf16
    int offg[4];   // element offset within matrix block (add ko each iter)
    int offl[4];   // ushort offset within LDS tile
#pragma unroll
    for (int p = 0; p < 4; ++p) {
        int slot = p * 256 + tid;        // [0,1024)
        int row = slot >> 3;             // [0,128)
        int pc = slot & 7;               // physical 16B chunk in row
        int lc = pc ^ (row & 7);         // logical k-chunk (XOR swizzle)
        offg[p] = row * IN_F + lc * 8;
        offl[p] = slot * 8;              // = row*64 + pc*8
    }
    const u16* baseA = A + (size_t)mb * IN_F;
    const u16* baseB = B + (size_t)nb * IN_F;

    // bias for this thread's 4 output columns, loaded before the K-loop
    float bj[4];
#pragma unroll
    for (int j = 0; j < 4; ++j)
        bj[j] = bias[nb + wc * 64 + j * 16 + ln];

    // fragment read row bases (ushort offsets; row stride = 64 ushorts)
    int arow[4], brow[4];
#pragma unroll
    for (int i = 0; i < 4; ++i) {
        arow[i] = (wr * 64 + i * 16 + ln) * 64;
        brow[i] = (wc * 64 + i * 16 + ln) * 64;
    }
    const int lnx = ln & 7;

    f32x4 acc[4][4];
#pragma unroll
    for (int i = 0; i < 4; ++i)
#pragma unroll
        for (int j = 0; j < 4; ++j) acc[i][j] = (f32x4)0.0f;

    for (int ko = 0; ko < IN_F; ko += 64) {
#pragma unroll
        for (int p = 0; p < 4; ++p)
            async_copy16(baseA + offg[p] + ko, &sA[offl[p]]);
#pragma unroll
        for (int p = 0; p < 4; ++p)
            async_copy16(baseB + offg[p] + ko, &sB[offl[p]]);
        __syncthreads();

#pragma unroll
        for (int kk = 0; kk < 2; ++kk) {
            const int pc8 = ((kk * 4 + quad) ^ lnx) * 8;
            bf16x8 av[4], bv[4];
#pragma unroll
            for (int i = 0; i < 4; ++i)
                av[i] = *(const bf16x8*)&sA[arow[i] + pc8];
#pragma unroll
            for (int j = 0; j < 4; ++j)
                bv[j] = *(const bf16x8*)&sB[brow[j] + pc8];
#pragma unroll
            for (int i = 0; i < 4; ++i)
#pragma unroll
                for (int j = 0; j < 4; ++j)
                    acc[i][j] = __builtin_amdgcn_mfma_f32_16x16x32_bf16(
                        av[i], bv[j], acc[i][j], 0, 0, 0);
        }
        __syncthreads();
    }

    // epilogue: C[row][col] = acc + bias[col]
#pragma unroll
    for (int i = 0; i < 4; ++i) {
        int mrow = mb + wr * 64 + i * 16 + quad * 4;
#pragma unroll
        for (int j = 0; j < 4; ++j) {
            int col = nb + wc * 64 + j * 16 + ln;
            float* cp = C + (size_t)mrow * OUT_F + col;
#pragma unroll
            for (int r = 0; r < 4; ++r)
                cp[(size_t)r * OUT_F] = acc[i][j][r] + bj[j];
        }
    }
}

extern "C" void kernel_launch(void* const* d_in, const int* in_sizes, int n_in,
                              void* d_out, int out_size, void* d_ws, size_t ws_size,
                              hipStream_t stream) {
    const float* x = (const float*)d_in[0];       // [2,2048,4096] fp32
    const int* wq = (const int*)d_in[1];          // [NUM_GROUPS*12]
    const float* wn = (const float*)d_in[2];      // [NUM_GROUPS]
    const float* bias = (const float*)d_in[3];    // [4096]
    float* out = (float*)d_out;                   // [2,2048,4096] fp32

    u16* Wb = (u16*)d_ws;                         // 32 MB
    u16* Xb = Wb + (size_t)OUT_F * IN_F;          // 32 MB

    // 8192 dequant blocks + 8192 cvt blocks in one launch
    prep_kernel<<<16384, 256, 0, stream>>>(x, wq, wn, Wb, Xb);
    gemm_bt_kernel<<<dim3(OUT_F / 128, M_ROWS / 128), 256, 0, stream>>>(
        Xb, Wb, bias, out);
}